// Round 17
// baseline (211.526 us; speedup 1.0000x reference)
//
#include <hip/hip_runtime.h>

// Problem constants (fixed by the reference):
#define NN    40000
#define EE    640000
#define INC   128
#define HID   256
#define OUTC  10
#define GG    64
#define CAP   64        // CSR slot capacity per node (max in-degree << 64 for E/N=16)

typedef unsigned short u16;
typedef unsigned char  u8;
typedef __attribute__((ext_vector_type(8))) short short8;   // 8 bf16 (4 VGPRs)
typedef __attribute__((ext_vector_type(4))) float f32x4;    // MFMA acc
typedef __attribute__((ext_vector_type(2))) float f32x2;    // cvt_pk output

__device__ __forceinline__ float bf2f(u16 h) {
    return __uint_as_float(((unsigned)h) << 16);
}
__device__ __forceinline__ u16 f2bf(float f) {   // round-to-nearest-even
    unsigned u = __float_as_uint(f);
    unsigned r = u + 0x7FFFu + ((u >> 16) & 1u);
    return (u16)(r >> 16);
}
// fp8 e4m3 (OCP on gfx950) encode/decode via HW cvt — R31-proven.
__device__ __forceinline__ u8 f2fp8(float v) {
    int r = 0;
    asm("v_cvt_pk_fp8_f32 %0, %1, %2" : "+v"(r) : "v"(v), "v"(v));
    return (u8)(r & 0xFF);
}
__device__ __forceinline__ f32x2 fp8pair(unsigned lo16) {   // decodes 2 fp8 in bits [15:0]
    f32x2 f;
    asm("v_cvt_pk_f32_fp8 %0, %1" : "=v"(f) : "v"(lo16));
    return f;
}

// async global->LDS, 16 B per lane (mgemm staging only — R21's gather-to-LDS
// agg FAILED correctness; DO NOT RETRY).
__device__ __forceinline__ void gload_lds16(const u16* g, u16* l) {
    __builtin_amdgcn_global_load_lds(
        (const __attribute__((address_space(1))) unsigned int*)g,
        (__attribute__((address_space(3))) unsigned int*)l,
        16, 0, 0);
}

// ---------------------------------------------------------------------------
// build: ONE kernel, three independent segments (R33: xq segment moved to
// xscale_kernel — baking d_n into xq needs FINAL cnt. R29 coop fusion CLOSED).
//  [0, e4)        : edge pass — rank = cnt[dst]++ ; col[dst*CAP+rank]=src
//  [e4, e4+WTOT)  : weight transpose, SINGLE bf16 (R28-proven)
//  [.., +GG+1)    : gseg[g] = lower_bound(batch, g)
// build profile (R31/R32): ~43-45 us, VALU 2%, WRITE 42 MB (2B col-store line
// amplification) — scatter/latency-bound on the atomic edge pass.
#define WTOT (INC * HID + HID * HID)
__global__ void build_kernel(const int* __restrict__ src, const int* __restrict__ dst,
                             int* __restrict__ cnt, u16* __restrict__ col, int e4,
                             const float* __restrict__ W1, u16* __restrict__ w1h,
                             const float* __restrict__ W2, u16* __restrict__ w2h,
                             const int* __restrict__ batch, int* __restrict__ gseg) {
    int i = blockIdx.x * blockDim.x + threadIdx.x;
    if (i < e4) {
        int4 d = ((const int4*)dst)[i];
        int4 s = ((const int4*)src)[i];
        int r0 = atomicAdd(&cnt[d.x], 1);
        int r1 = atomicAdd(&cnt[d.y], 1);
        int r2 = atomicAdd(&cnt[d.z], 1);
        int r3 = atomicAdd(&cnt[d.w], 1);
        if (r0 < CAP) col[(d.x << 6) + r0] = (u16)s.x;
        if (r1 < CAP) col[(d.y << 6) + r1] = (u16)s.y;
        if (r2 < CAP) col[(d.z << 6) + r2] = (u16)s.z;
        if (r3 < CAP) col[(d.w << 6) + r3] = (u16)s.w;
    } else if (i < e4 + WTOT) {
        int idx = i - e4;
        const float* W; u16* Th; int K;
        if (idx < INC * HID) { W = W1; Th = w1h; K = INC; }
        else { W = W2; Th = w2h; K = HID; idx -= INC * HID; }
        int k = idx >> 8;          // /256
        int n = idx & 255;
        Th[(size_t)n * K + k] = f2bf(W[idx]);   // LOCAL idx (R28 bugfix)
    } else {
        int g = i - e4 - WTOT;
        if (g <= GG) {
            int lo = 0, hi = NN;
            while (lo < hi) { int mid = (lo + hi) >> 1; if (batch[mid] < g) lo = mid + 1; else hi = mid; }
            gseg[g] = lo;
        }
    }
}

// ---------------------------------------------------------------------------
// R33: xq = fp8(rsqrt(cnt[n]+1) * x[n]) — pre-scaled fp8 features. Removes
// agg1's per-item cnt-gather stream entirely (the structural asymmetry vs the
// 27-us agg2: at fp8 the cnt gathers became the critical path — R22's neutral
// at bf16 was a different regime, rows were byte-bound then). Runs after
// build (cnt final). Streaming 20.5 MB read + 5.1 MB write ≈ 5 us.
__global__ __launch_bounds__(256) void xscale_kernel(
    const float* __restrict__ x, const int* __restrict__ cnt,
    u8* __restrict__ xq, int total4) {
    int j = blockIdx.x * blockDim.x + threadIdx.x;   // one float4 per thread
    if (j >= total4) return;
    int n = j >> 5;                                  // 32 float4 per 128-f32 row
    float dn = rsqrtf((float)(cnt[n] + 1));
    float4 v = ((const float4*)x)[j];
    unsigned o = (unsigned)f2fp8(v.x * dn) | ((unsigned)f2fp8(v.y * dn) << 8)
               | ((unsigned)f2fp8(v.z * dn) << 16) | ((unsigned)f2fp8(v.w * dn) << 24);
    ((unsigned*)xq)[j] = o;
}

// ---------------------------------------------------------------------------
// MFMA GEMM (R20/R26/R28-proven staging — do not touch).
// C[M, 256] = A[M,K](bf16) @ Wh[K,256] (stored transposed [256][K] bf16).
//  MODE 0: store FP8 e4m3 of (rsqrt(cnt[m]+1)*relu(v)) to Cout  (R31-proven)
//  MODE 1: accumulate v into pooled[batch[m]][n]  (layer 2 + pool phase 1)
// FAILED, do not retry: R16 BM=64; R19 reg-staged LDS dbuf; R29 coop fusion.
#define BM 128
#define BN 128
#define BK 64
#define PGL 8    // max local graphs per 128-row tile (avg graph = 625 nodes)

template<int MODE>
__global__ __launch_bounds__(256) void mgemm_kernel(
    const u16* __restrict__ A,   // [M,K] bf16
    const u16* __restrict__ Bh,  // [256,K] bf16 (W^T)
    const float* __restrict__ bias,
    const int* __restrict__ cnt,
    u8* __restrict__ Cout,       // MODE 0: fp8 [M][256]
    const int* __restrict__ batch, float* __restrict__ pooled,
    int M, int K)
{
    __shared__ __align__(16) u16 As [BM * BK];   // 16 KB, row = 128 B
    __shared__ __align__(16) u16 Bhs[BN * BK];   // 16 KB
    __shared__ float ptile[MODE == 1 ? PGL * BN : 1];   // 4 KB in MODE 1 only

    const int tid  = threadIdx.x;
    const int lane = tid & 63;
    const int wave = tid >> 6;
    const int ln   = lane & 15;        // col within 16x16 tile
    const int qd   = lane >> 4;        // quad: k-unit for A/B frags, row-quad for C
    const int wm   = (wave & 1) * 64;  // wave m-offset in tile
    const int wn   = (wave >> 1) * 64; // wave n-offset in tile
    const int m0   = blockIdx.x * BM;
    const int n0   = blockIdx.y * BN;

    f32x4 acc[4][4];
#pragma unroll
    for (int i = 0; i < 4; ++i)
#pragma unroll
        for (int j = 0; j < 4; ++j) acc[i][j] = (f32x4)(0.0f);

    if (MODE == 1) {
        for (int t = tid; t < PGL * BN; t += 256) ptile[t] = 0.0f;
    }

    // staging lane roles: each wave-load covers 8 rows x 128 B (1 KB LDS)
    const int rl = lane >> 3;          // row within 8-row group (0..7)
    const int su = lane & 7;           // 16B chunk slot within row (0..7)

    for (int k0 = 0; k0 < K; k0 += BK) {
        // ---- stage chunk k0: 8 async wave-loads, no VGPR round trip ----
#pragma unroll
        for (int L = 0; L < 4; ++L) {
            int rloc = (wave * 4 + L) * 8 + rl;             // 0..127
            int sv   = (su ^ (rloc & 7)) * 8;               // swizzled src chunk
            int ga   = m0 + rloc; if (ga >= M) ga = M - 1;  // clamp; rows>=M never read back
            gload_lds16(A  + (size_t)ga * K          + k0 + sv, As  + (size_t)(wave * 4 + L) * 512);
            gload_lds16(Bh + (size_t)(n0 + rloc) * K + k0 + sv, Bhs + (size_t)(wave * 4 + L) * 512);
        }
        __syncthreads();   // drains vmcnt(0): tiles ready

        // ---- two 32-wide K-steps from the 64-wide chunk ----
#pragma unroll
        for (int ks = 0; ks < 2; ++ks) {
            const int fsw = ((ks * 4 + qd) ^ (ln & 7)) * 8;   // read slot (u16)
            short8 af[4], bfh[4];
#pragma unroll
            for (int t = 0; t < 4; ++t) {
                af[t]  = *(const short8*)(As  + (wm + t * 16 + ln) * BK + fsw);
                bfh[t] = *(const short8*)(Bhs + (wn + t * 16 + ln) * BK + fsw);
            }
#pragma unroll
            for (int ti = 0; ti < 4; ++ti)
#pragma unroll
                for (int tj = 0; tj < 4; ++tj)
                    acc[ti][tj] = __builtin_amdgcn_mfma_f32_16x16x32_bf16(
                        af[ti], bfh[tj], acc[ti][tj], 0, 0, 0);
        }
        __syncthreads();   // frag reads done before next chunk overwrites
    }

    // ---- epilogue: C layout col=lane&15, row=qd*4+reg ----
    float bcol[4];
#pragma unroll
    for (int tj = 0; tj < 4; ++tj) bcol[tj] = bias[n0 + wn + tj * 16 + ln];

    if (MODE == 0) {
#pragma unroll
        for (int ti = 0; ti < 4; ++ti) {
#pragma unroll
            for (int r = 0; r < 4; ++r) {
                int row = m0 + wm + ti * 16 + qd * 4 + r;
                if (row < M) {
                    float dm = rsqrtf((float)(cnt[row] + 1));
                    u8* crow = Cout + (size_t)row * HID;
#pragma unroll
                    for (int tj = 0; tj < 4; ++tj) {
                        float v = fmaxf(acc[ti][tj][r] + bcol[tj], 0.0f);
                        crow[n0 + wn + tj * 16 + ln] = f2fp8(v * dm);
                    }
                }
            }
        }
    } else {
        // cache graph ids of this thread's 16 rows
        int bg[16];
#pragma unroll
        for (int ti = 0; ti < 4; ++ti)
#pragma unroll
            for (int r = 0; r < 4; ++r) {
                int row = m0 + wm + ti * 16 + qd * 4 + r;
                bg[ti * 4 + r] = (row < M) ? batch[row] : -1;
            }
        const int g_lo = batch[m0];
        const int g_hi = batch[min(m0 + BM, M) - 1];
        for (int g = g_lo; g <= g_hi; ++g) {
            float cs[4] = {0.0f, 0.0f, 0.0f, 0.0f};
#pragma unroll
            for (int ti = 0; ti < 4; ++ti)
#pragma unroll
                for (int r = 0; r < 4; ++r)
                    if (bg[ti * 4 + r] == g) {
#pragma unroll
                        for (int tj = 0; tj < 4; ++tj)
                            cs[tj] += fmaxf(acc[ti][tj][r] + bcol[tj], 0.0f);
                    }
            // fold the 4 qd lanes holding the same column (lane bits 16, 32)
#pragma unroll
            for (int tj = 0; tj < 4; ++tj) {
                cs[tj] += __shfl_xor(cs[tj], 16);
                cs[tj] += __shfl_xor(cs[tj], 32);
            }
            if (qd == 0) {
                int gl = g - g_lo;
#pragma unroll
                for (int tj = 0; tj < 4; ++tj) {
                    int c = wn + tj * 16 + ln;
                    if (gl < PGL) atomicAdd(&ptile[gl * BN + c], cs[tj]);
                    else atomicAdd(&pooled[(size_t)g * HID + n0 + c], cs[tj]);
                }
            }
        }
        __syncthreads();
        const int g0 = batch[m0];
        for (int t = tid; t < PGL * BN; t += 256) {
            float v = ptile[t];
            if (v != 0.0f) {
                int gl = t / BN, c = t % BN;
                atomicAdd(&pooled[(size_t)(g0 + gl) * HID + n0 + c], v);
            }
        }
    }
}

// ---------------------------------------------------------------------------
// R33: agg1 over pre-scaled FP8 xq — SUM-ONLY, structurally identical to the
// 27-us agg2_fp8 (no cnt gathers, no per-item scale) at half the row bytes.
// Rows 128 B: 2 gathers + 2 col loads per 16 items. out = bf16(d_n * sum).
// CLOSED avenues (do not retry): R8 UFx2, R10 2-waves/node, R13 src-partition,
// R19 shfl-hoist, R21 gather-to-LDS, R23 %8-slice, R24/R25 XCC slicing,
// R29 coop fusion. R32 (fp8 with cnt gathers kept) was ~neutral — the cnt
// stream was the binding term, hence this round.
__global__ __launch_bounds__(256) void agg1_fp8_kernel(
    const u8* __restrict__ xq,    // [NN][128] fp8, pre-scaled by d_src
    const int* __restrict__ cnt,
    const u16* __restrict__ col, u16* __restrict__ out, int n_nodes)
{
    const int lane = threadIdx.x & 63;
    const int n    = (blockIdx.x * blockDim.x + threadIdx.x) >> 6;  // wave id
    if (n >= n_nodes) return;
    const int li = lane & 7;      // 16 B slot within 128 B row (cols li*16..+15)
    const int gi = lane >> 3;     // item slot 0..7

    const int base0 = n << 6;
    const int total = 1 + cnt[n];

    float acc[16];
#pragma unroll
    for (int i = 0; i < 16; ++i) acc[i] = 0.0f;

    for (int base = 0; base < total; base += 16) {   // 8 slots x 2 unroll
        int idxs[2]; bool valid[2];
#pragma unroll
        for (int u = 0; u < 2; ++u) {
            int it = base + u * 8 + gi;
            valid[u] = (it < total);
            idxs[u] = 0;
            if (valid[u]) idxs[u] = (it == 0) ? n : (int)col[base0 + it - 1];
        }
        uint4 w[2];
#pragma unroll
        for (int u = 0; u < 2; ++u)
            if (valid[u])
                w[u] = *(const uint4*)(xq + (size_t)idxs[u] * INC + li * 16);
#pragma unroll
        for (int u = 0; u < 2; ++u)
            if (valid[u]) {
                unsigned uu[4] = {w[u].x, w[u].y, w[u].z, w[u].w};
#pragma unroll
                for (int q = 0; q < 4; ++q) {
                    f32x2 lo = fp8pair(uu[q] & 0xFFFFu);
                    f32x2 hi = fp8pair(uu[q] >> 16);
                    acc[4 * q + 0] += lo[0];
                    acc[4 * q + 1] += lo[1];
                    acc[4 * q + 2] += hi[0];
                    acc[4 * q + 3] += hi[1];
                }
            }
    }

    // fold the 8 item slots (lane bits 3, 4, 5)
#pragma unroll
    for (int off = 32; off >= 8; off >>= 1)
#pragma unroll
        for (int i = 0; i < 16; ++i)
            acc[i] += __shfl_xor(acc[i], off);

    if (gi == 0) {                 // lanes 0..7: lane li writes cols li*16..+15
        float d = rsqrtf((float)total);
        unsigned r[8];
#pragma unroll
        for (int q = 0; q < 8; ++q) {
            unsigned l16 = (unsigned)f2bf(acc[2 * q] * d);
            unsigned h16 = (unsigned)f2bf(acc[2 * q + 1] * d);
            r[q] = l16 | (h16 << 16);
        }
        uint4* o = (uint4*)(out + (size_t)n * INC + li * 16);
        o[0] = make_uint4(r[0], r[1], r[2], r[3]);
        o[1] = make_uint4(r[4], r[5], r[6], r[7]);
    }
}

// ---------------------------------------------------------------------------
// R31: agg2 over FP8 h1s — PROVEN (48 -> ~27 us; total -21.5). PERMANENT.
__global__ __launch_bounds__(256) void agg2_fp8_kernel(
    const u8* __restrict__ hs,    // [NN][256] fp8
    const int* __restrict__ cnt,
    const u16* __restrict__ col, u16* __restrict__ out, int n_nodes)
{
    const int lane = threadIdx.x & 63;
    const int n    = (blockIdx.x * blockDim.x + threadIdx.x) >> 6;  // wave id
    if (n >= n_nodes) return;
    const int li = lane & 15;     // 16 B slot within 256 B row (cols li*16..+15)
    const int gi = lane >> 4;     // item slot 0..3

    const int base0 = n << 6;
    const int total = 1 + cnt[n];

    float acc[16];
#pragma unroll
    for (int i = 0; i < 16; ++i) acc[i] = 0.0f;

    for (int base = 0; base < total; base += 16) {   // 4 slots x 4 unroll
        int idxs[4]; bool valid[4];
#pragma unroll
        for (int u = 0; u < 4; ++u) {
            int it = base + u * 4 + gi;
            valid[u] = (it < total);
            idxs[u] = 0;
            if (valid[u]) idxs[u] = (it == 0) ? n : (int)col[base0 + it - 1];
        }
        uint4 w[4];
#pragma unroll
        for (int u = 0; u < 4; ++u)
            if (valid[u])
                w[u] = *(const uint4*)(hs + (size_t)idxs[u] * HID + li * 16);
#pragma unroll
        for (int u = 0; u < 4; ++u)
            if (valid[u]) {
                unsigned uu[4] = {w[u].x, w[u].y, w[u].z, w[u].w};
#pragma unroll
                for (int q = 0; q < 4; ++q) {
                    f32x2 lo = fp8pair(uu[q] & 0xFFFFu);
                    f32x2 hi = fp8pair(uu[q] >> 16);
                    acc[4 * q + 0] += lo[0];
                    acc[4 * q + 1] += lo[1];
                    acc[4 * q + 2] += hi[0];
                    acc[4 * q + 3] += hi[1];
                }
            }
    }

    // fold the 4 item slots (lane bits 16, 32)
#pragma unroll
    for (int off = 32; off >= 16; off >>= 1)
#pragma unroll
        for (int i = 0; i < 16; ++i)
            acc[i] += __shfl_xor(acc[i], off);

    if (gi == 0) {                 // lanes 0..15: lane li writes cols li*16..+15
        float d = rsqrtf((float)total);
        unsigned r[8];
#pragma unroll
        for (int q = 0; q < 8; ++q) {
            unsigned l16 = (unsigned)f2bf(acc[2 * q] * d);
            unsigned h16 = (unsigned)f2bf(acc[2 * q + 1] * d);
            r[q] = l16 | (h16 << 16);
        }
        uint4* o = (uint4*)(out + (size_t)n * HID + li * 16);
        o[0] = make_uint4(r[0], r[1], r[2], r[3]);
        o[1] = make_uint4(r[4], r[5], r[6], r[7]);
    }
}

// ---------------------------------------------------------------------------
// Pool finalize (gseg precomputed in build — no serial binary searches).
__global__ __launch_bounds__(256) void pool_finalize_kernel(
    const float* __restrict__ pooled, const int* __restrict__ gseg,
    const float* __restrict__ Wlin, const float* __restrict__ blin,
    float* __restrict__ out)
{
    const int g = blockIdx.x;
    const int j = threadIdx.x;
    const int cntg = gseg[g + 1] - gseg[g];

    float pv = pooled[(size_t)g * HID + j] / fmaxf((float)cntg, 1.0f);

    __shared__ float pl[HID];
    pl[j] = pv;
    __syncthreads();
    if (j < OUTC) {
        float o = blin[j];
        for (int k = 0; k < HID; ++k) o = fmaf(pl[k], Wlin[k * OUTC + j], o);
        out[g * OUTC + j] = o;
    }
}

// ---------------------------------------------------------------------------
extern "C" void kernel_launch(void* const* d_in, const int* in_sizes, int n_in,
                              void* d_out, int out_size, void* d_ws, size_t ws_size,
                              hipStream_t stream) {
    const float* x     = (const float*)d_in[0];
    const int*   ei    = (const int*)  d_in[1];   // [2, E]: row0 src, row1 dst
    const int*   batch = (const int*)  d_in[2];
    const float* W1    = (const float*)d_in[3];
    const float* b1    = (const float*)d_in[4];
    const float* W2    = (const float*)d_in[5];
    const float* b2    = (const float*)d_in[6];
    const float* Wlin  = (const float*)d_in[7];
    const float* blin  = (const float*)d_in[8];
    float* out = (float*)d_out;

    const int* src = ei;
    const int* dst = ei + EE;

    // workspace layout. [pooled|cnt] contiguous (zero region); gseg after col.
    char* p = (char*)d_ws;
    u8*    xq  = (u8*)p;    p += (size_t)NN * INC * sizeof(u16);    // fp8 uses half; slot kept
    u16*   xab = (u16*)p;   p += (size_t)NN * INC * sizeof(u16);    // 10.24 MB
    u8*    h1s = (u8*)p;    p += (size_t)NN * HID * sizeof(u16);    // fp8 uses half; slot kept
    u16*   a2b = (u16*)p;   p += (size_t)NN * HID * sizeof(u16);    // 20.48 MB
    u16*   w1h = (u16*)p;   p += (size_t)HID * INC * sizeof(u16);
    u16*   w2h = (u16*)p;   p += (size_t)HID * HID * sizeof(u16);
    char* zbase = p;                                         // zero region:
    float* pooled = (float*)p; p += (size_t)GG * HID * sizeof(float); //  pooled
    int* cnt    = (int*)p;  p += (size_t)NN * sizeof(int);            //  cnt
    size_t zbytes = (size_t)(p - zbase);
    u16* col    = (u16*)p;  p += (size_t)NN * CAP * sizeof(u16);      // 5.12 MB
    int* gseg   = (int*)p;  p += (GG + 1) * sizeof(int);
    (void)ws_size; (void)n_in; (void)in_sizes; (void)out_size;

    const int TB = 256;
    const int e4     = EE / 4;                  // EE divisible by 4
    const int total4 = NN * INC / 4;
    const int build_threads = e4 + WTOT + GG + 1;
    const int nb_build = (build_threads + TB - 1) / TB;

    // structure pass (rebuilt every call; ws re-poisoned)
    hipMemsetAsync(zbase, 0, zbytes, stream);
    build_kernel<<<nb_build, TB, 0, stream>>>(src, dst, cnt, col, e4,
                                              W1, w1h, W2, w2h, batch, gseg);
    // pre-scaled fp8 features (needs final cnt)
    xscale_kernel<<<(total4 + TB - 1) / TB, TB, 0, stream>>>(x, cnt, xq, total4);

    dim3 ggrid((NN + BM - 1) / BM, HID / BN);   // 313 x 2 blocks
    const int agg_blocks = (NN * 64 + TB - 1) / TB;   // one wave per node

    // layer 1: xab = bf16(d_n .* sum xq[idx]);  h1s = fp8(d_m .* relu(xab@W1 + b1))
    agg1_fp8_kernel<<<agg_blocks, TB, 0, stream>>>(xq, cnt, col, xab, NN);
    mgemm_kernel<0><<<ggrid, 256, 0, stream>>>(xab, w1h, b1, cnt, h1s,
                                               batch, pooled, NN, INC);

    // layer 2: a2b = bf16(d_n .* sum fp8dec(h1s[idx]));
    // gemm2 fuses relu(a2b@W2 + b2) with pool phase 1 (conflict-free reduction)
    agg2_fp8_kernel<<<agg_blocks, TB, 0, stream>>>(h1s, cnt, col, a2b, NN);
    mgemm_kernel<1><<<ggrid, 256, 0, stream>>>(a2b, w2h, b2, cnt, (u8*)nullptr,
                                               batch, pooled, NN, HID);

    // pool finalize (gseg-based) + linear
    pool_finalize_kernel<<<GG, 256, 0, stream>>>(pooled, gseg, Wlin, blin, out);
}